// Round 3
// baseline (285.350 us; speedup 1.0000x reference)
//
#include <hip/hip_runtime.h>
#include <hip/hip_bf16.h>
#include <stdint.h>

// ---------------- common types / helpers ----------------

typedef __bf16 bf16x8 __attribute__((ext_vector_type(8)));
typedef float  f32x4  __attribute__((ext_vector_type(4)));
typedef float  f32x16 __attribute__((ext_vector_type(16)));
typedef short  s16x8  __attribute__((ext_vector_type(8)));
typedef unsigned int u32x4 __attribute__((ext_vector_type(4)));

__device__ __forceinline__ f32x4 mfma_bf16(s16x8 a, s16x8 b, f32x4 c) {
  return __builtin_amdgcn_mfma_f32_16x16x32_bf16(
      __builtin_bit_cast(bf16x8, a), __builtin_bit_cast(bf16x8, b), c, 0, 0, 0);
}

__device__ __forceinline__ f32x16 mfma32(s16x8 a, s16x8 b, f32x16 c) {
  return __builtin_amdgcn_mfma_f32_32x32x16_bf16(
      __builtin_bit_cast(bf16x8, a), __builtin_bit_cast(bf16x8, b), c, 0, 0, 0);
}

__device__ __forceinline__ unsigned short f2bf(float f) {
  unsigned u = __float_as_uint(f);
  u = u + 0x7FFFu + ((u >> 16) & 1u);   // RNE
  return (unsigned short)(u >> 16);
}

__device__ __forceinline__ unsigned cvt_pk_bf16(float lo, float hi) {
  unsigned r;
  asm("v_cvt_pk_bf16_f32 %0, %1, %2" : "=v"(r) : "v"(lo), "v"(hi));
  return r;
}

__device__ __forceinline__ void load_lds16(const void* g, void* l) {
  __builtin_amdgcn_global_load_lds(
      (const __attribute__((address_space(1))) void*)g,
      (__attribute__((address_space(3))) void*)l, 16, 0, 0);
}

// ---------------- fused cast fp32 -> bf16 (x, Wqkv, Wproj in one launch) ----------------

__global__ void cast3_kernel(const float* __restrict__ x, const float* __restrict__ wq,
                             const float* __restrict__ wp,
                             unsigned short* __restrict__ xb,
                             unsigned short* __restrict__ wqb,
                             unsigned short* __restrict__ wpb) {
  // sizes in float4 units: x 2097152, wq 786432, wp 262144 (total 3145728)
  int i = blockIdx.x * blockDim.x + threadIdx.x;
  int stride = gridDim.x * blockDim.x;
  for (; i < 3145728; i += stride) {
    const float4* src; ushort4* dst; int j;
    if (i < 2097152)      { src = (const float4*)x;  dst = (ushort4*)xb;  j = i; }
    else if (i < 2883584) { src = (const float4*)wq; dst = (ushort4*)wqb; j = i - 2097152; }
    else                  { src = (const float4*)wp; dst = (ushort4*)wpb; j = i - 2883584; }
    float4 v = src[j];
    ushort4 o;
    o.x = f2bf(v.x); o.y = f2bf(v.y); o.z = f2bf(v.z); o.w = f2bf(v.w);
    dst[j] = o;
  }
}

// ---------------- GEMM 256x256, BK=64, 8-phase counted-vmcnt schedule ----------------
// C[M,N] = A[M,K] * B[N,K]^T, bf16 in, fp32 acc. 512 threads = 8 waves (2M x 4N),
// per-wave output 128x64. LDS: 2 bufs x (A 32KB + B 32KB) = 128KB.
// A stored qm-major: r' = qm*128 + wm*64 + m; rows of 64 shorts (128B), 16B-slot
// XOR swizzle slot^(r&7), staged via global_load_lds with pre-swizzled source.
// Staging groups per K-tile (2 loads/wave each): g0 = B rows 0-127, g1 = B rows
// 128-255, g2 = A r' 0-127 (qm=0), g3 = A r' 128-255 (qm=1). Group g issued at
// phase g of the PREVIOUS K-tile. Counted waits (per-wave ledger, never 0 in
// steady state): end p1 -> vmcnt(4) [drains g3(t); leaves g0,g1(t+1)];
// end p3 -> vmcnt(2) [drains g0-g2(t+1); leaves g3(t+1)].

template <bool OUT_BF16>
__global__ __launch_bounds__(512, 2)
void gemm256(const short* __restrict__ A, const short* __restrict__ Bw,
             void* __restrict__ Cp, int M, int N, int K) {
  __shared__ __align__(16) short a_lds[2][256 * 64];
  __shared__ __align__(16) short b_lds[2][256 * 64];

  const int nbn = N >> 8;
  const int nwg = gridDim.x;             // multiple of 8 for both call sites
  const int q8 = nwg >> 3;
  const int swz = (blockIdx.x & 7) * q8 + (blockIdx.x >> 3);
  const int mb = swz / nbn, nb = swz % nbn;

  const int tid = threadIdx.x;
  const int w = tid >> 6, l = tid & 63;
  const int lg = l >> 4, ll = l & 15;
  const int wm = w >> 2, wn = w & 3;

  f32x4 acc[8][4];
#pragma unroll
  for (int i = 0; i < 8; ++i)
#pragma unroll
    for (int j = 0; j < 4; ++j) acc[i][j] = {0.f, 0.f, 0.f, 0.f};

  const int NT = K >> 6;

  // issue 2 global_load_lds for group g of tile t into buf t&1
  auto stage = [&](int t, int g) {
    short* lptr = (g < 2) ? b_lds[t & 1] : a_lds[t & 1];
    const short* gp = (g < 2) ? Bw : A;
    const int gg = g & 1;
#pragma unroll
    for (int j = 0; j < 2; ++j) {
      int r0 = gg * 128 + w * 16 + j * 8;     // LDS row base (8 rows per load)
      int rl = r0 + (l >> 3);                 // this lane's LDS row
      int grow;
      if (g < 2) grow = nb * 256 + rl;
      else       grow = mb * 256 + ((rl >> 6) & 1) * 128 + (rl >> 7) * 64 + (rl & 63);
      const short* src = gp + (size_t)grow * K + t * 64 + (((l & 7) ^ (l >> 3)) << 3);
      load_lds16(src, lptr + r0 * 64);
    }
  };

#define GQ_PHASE(QM, KK, GG, ...)                                              \
  {                                                                            \
    const short* ab = a_lds[cur];                                              \
    const short* bb = b_lds[cur];                                              \
    const int slot = (((KK) * 4 + lg) ^ (ll & 7)) * 8;                         \
    s16x8 af[4], bfr[4];                                                       \
    _Pragma("unroll") for (int mi = 0; mi < 4; ++mi)                           \
      af[mi] = *reinterpret_cast<const s16x8*>(                                \
          ab + ((QM) * 128 + wm * 64 + mi * 16 + ll) * 64 + slot);             \
    _Pragma("unroll") for (int nj = 0; nj < 4; ++nj)                           \
      bfr[nj] = *reinterpret_cast<const s16x8*>(                               \
          bb + (wn * 64 + nj * 16 + ll) * 64 + slot);                          \
    if (pf) stage(t + 1, (GG));                                                \
    __builtin_amdgcn_s_barrier();                                              \
    asm volatile("s_waitcnt lgkmcnt(0)" ::: "memory");                         \
    __builtin_amdgcn_sched_barrier(0);                                         \
    __builtin_amdgcn_s_setprio(1);                                             \
    _Pragma("unroll") for (int mi = 0; mi < 4; ++mi)                           \
      _Pragma("unroll") for (int nj = 0; nj < 4; ++nj)                         \
        acc[(QM) * 4 + mi][nj] = mfma_bf16(af[mi], bfr[nj], acc[(QM) * 4 + mi][nj]); \
    __builtin_amdgcn_s_setprio(0);                                             \
    __VA_ARGS__                                                                \
    __builtin_amdgcn_s_barrier();                                              \
  }

  // prologue: all 4 groups of tile 0; need g0-g2 before phase 0
  stage(0, 0); stage(0, 1); stage(0, 2); stage(0, 3);
  asm volatile("s_waitcnt vmcnt(2)" ::: "memory");
  __builtin_amdgcn_s_barrier();

  for (int t = 0; t < NT; ++t) {
    const int cur = t & 1;
    const bool pf = (t + 1 < NT);
    GQ_PHASE(0, 0, 0, )
    GQ_PHASE(0, 1, 1,
      if (pf) { asm volatile("s_waitcnt vmcnt(4)" ::: "memory"); }
      else    { asm volatile("s_waitcnt vmcnt(0)" ::: "memory"); })
    GQ_PHASE(1, 0, 2, )
    GQ_PHASE(1, 1, 3,
      if (pf) { asm volatile("s_waitcnt vmcnt(2)" ::: "memory"); }
      else    { asm volatile("s_waitcnt vmcnt(0)" ::: "memory"); })
  }
#undef GQ_PHASE

  // epilogue: C/D layout col = lane&15, row = lg*4 + i
#pragma unroll
  for (int qm = 0; qm < 2; ++qm)
#pragma unroll
    for (int mi = 0; mi < 4; ++mi)
#pragma unroll
      for (int i = 0; i < 4; ++i) {
        size_t row = (size_t)(mb * 256 + wm * 128 + qm * 64 + mi * 16 + lg * 4 + i);
#pragma unroll
        for (int nj = 0; nj < 4; ++nj) {
          int col = nb * 256 + wn * 64 + nj * 16 + ll;
          if (OUT_BF16)
            ((unsigned short*)Cp)[row * N + col] = f2bf(acc[qm * 4 + mi][nj][i]);
          else
            ((float*)Cp)[row * N + col] = acc[qm * 4 + mi][nj][i];
        }
      }
}

// ---------------- flash attention: 8-wave, 32x32 MFMA, swapped QK^T ----------------

__global__ __launch_bounds__(512, 2)
void attn_fwd(const short* __restrict__ qkv, unsigned short* __restrict__ aout) {
  __shared__ __align__(16) short k_lds[2][64 * 128];   // [buf][krow][d] swizzled (32KB)
  __shared__ __align__(16) short v_lds[2][128 * 64];   // [buf][d][krow] swizzled (32KB)

  const int bh = blockIdx.x >> 3;
  const int qb = blockIdx.x & 7;
  const int b = bh >> 3, h = bh & 7;
  const int tid = threadIdx.x;
  const int w = tid >> 6, l = tid & 63;
  const int col = l & 31, hi = l >> 5;

  const size_t base = (size_t)b * 2048 * 3072 + (size_t)h * 128;
  const int qrow0 = qb * 256 + w * 32;

  s16x8 qf[8];
  {
    const short* qp = qkv + base + (size_t)(qrow0 + col) * 3072 + hi * 8;
#pragma unroll
    for (int ks = 0; ks < 8; ++ks)
      qf[ks] = *reinterpret_cast<const s16x8*>(qp + ks * 16);
  }

  f32x16 oacc[4];
#pragma unroll
  for (int nt = 0; nt < 4; ++nt)
#pragma unroll
    for (int r = 0; r < 16; ++r) oacc[nt][r] = 0.f;
  float M = -1e30f, L = 0.f;
  const float csc = 0.08838834764831845f * 1.4426950408889634f;  // scale*log2e

  s16x8 vr0a, vr0b, vr1a, vr1b;
  const int vr_r0 = (tid & 31) * 2;
  const int vr_c0 = ((tid >> 5) & 7) * 16;

  auto stage_k = [&](int kb, int bf) {
    int wk = w - 4;
#pragma unroll
    for (int cc = 0; cc < 4; ++cc) {
      int c = wk * 4 + cc;
      int row = c * 4 + (l >> 4);
      int sd = (l & 15) ^ (row & 7);
      load_lds16(qkv + base + 1024 + (size_t)(kb * 64 + row) * 3072 + sd * 8,
                 &k_lds[bf][c * 512]);
    }
  };
  auto load_v = [&](int kb) {
    const short* g = qkv + base + 2048 + (size_t)(kb * 64 + vr_r0) * 3072 + vr_c0;
    vr0a = *reinterpret_cast<const s16x8*>(g);
    vr0b = *reinterpret_cast<const s16x8*>(g + 8);
    vr1a = *reinterpret_cast<const s16x8*>(g + 3072);
    vr1b = *reinterpret_cast<const s16x8*>(g + 3072 + 8);
  };
  auto write_v = [&](int bf) {
    char* vbase = reinterpret_cast<char*>(v_lds[bf]);
#pragma unroll
    for (int j = 0; j < 16; ++j) {
      int d = vr_c0 + j;
      unsigned e0 = (unsigned short)(j < 8 ? vr0a[j] : vr0b[j - 8]);
      unsigned e1 = (unsigned short)(j < 8 ? vr1a[j] : vr1b[j - 8]);
      int byte = d * 128 + ((((vr_r0 * 2) >> 4) ^ (d & 7)) << 4) + ((vr_r0 * 2) & 15);
      *reinterpret_cast<unsigned*>(vbase + byte) = e0 | (e1 << 16);
    }
  };

  if (w >= 4) stage_k(0, 0);
  else { load_v(0); write_v(0); }
  __syncthreads();

  for (int kb = 0; kb < 32; ++kb) {
    const int bf = kb & 1;
    if (kb < 31) {
      if (w >= 4) stage_k(kb + 1, bf ^ 1);
      else load_v(kb + 1);
    }

    // ---- S^T = K Q^T
    f32x16 st[2];
#pragma unroll
    for (int kt = 0; kt < 2; ++kt)
#pragma unroll
      for (int r = 0; r < 16; ++r) st[kt][r] = 0.f;
    const char* kbase = reinterpret_cast<const char*>(k_lds[bf]);
    __builtin_amdgcn_s_setprio(1);
#pragma unroll
    for (int ks = 0; ks < 8; ++ks) {
#pragma unroll
      for (int kt = 0; kt < 2; ++kt) {
        int krow = kt * 32 + col;
        int slot = (ks * 2 + hi) ^ (krow & 7);
        s16x8 ak = *reinterpret_cast<const s16x8*>(kbase + krow * 256 + slot * 16);
        st[kt] = mfma32(ak, qf[ks], st[kt]);
      }
    }
    __builtin_amdgcn_s_setprio(0);

    // ---- online softmax (lane owns q-row = col; partner = lane^32)
    float pm = st[0][0];
#pragma unroll
    for (int r = 1; r < 16; ++r) pm = fmaxf(pm, st[0][r]);
#pragma unroll
    for (int r = 0; r < 16; ++r) pm = fmaxf(pm, st[1][r]);
    pm *= csc;
    pm = fmaxf(pm, __shfl_xor(pm, 32));
    if (!__all(pm <= M + 8.0f)) {     // defer-max, THR=8 (exp2 domain)
      float Mn = fmaxf(M, pm);
      float f = exp2f(M - Mn);
      M = Mn; L *= f;
#pragma unroll
      for (int r = 0; r < 16; ++r) {
        float fr = __shfl(f, (r & 3) + 8 * (r >> 2) + 4 * hi);
#pragma unroll
        for (int nt = 0; nt < 4; ++nt) oacc[nt][r] *= fr;
      }
    }
    float rs = 0.f;
#pragma unroll
    for (int kt = 0; kt < 2; ++kt)
#pragma unroll
      for (int r = 0; r < 16; ++r) {
        float e = exp2f(fmaf(st[kt][r], csc, -M));
        st[kt][r] = e;
        rs += e;
      }
    rs += __shfl_xor(rs, 32);
    L += rs;

    // ---- P -> bf16 A-operand frags, in-register
    unsigned wd[16], pw[16];
#pragma unroll
    for (int i = 0; i < 8; ++i) {
      wd[i]     = cvt_pk_bf16(st[0][2 * i], st[0][2 * i + 1]);
      wd[8 + i] = cvt_pk_bf16(st[1][2 * i], st[1][2 * i + 1]);
    }
#pragma unroll
    for (int i = 0; i < 16; ++i) pw[i] = __shfl_xor(wd[i], 32);
    s16x8 pa[4];
#pragma unroll
    for (int kt = 0; kt < 2; ++kt) {
      int bq = kt * 8;
      u32x4 f0 = {hi ? pw[bq + 2] : wd[bq + 0], hi ? pw[bq + 3] : wd[bq + 1],
                  hi ? wd[bq + 2] : pw[bq + 0], hi ? wd[bq + 3] : pw[bq + 1]};
      u32x4 f1 = {hi ? pw[bq + 6] : wd[bq + 4], hi ? pw[bq + 7] : wd[bq + 5],
                  hi ? wd[bq + 6] : pw[bq + 4], hi ? wd[bq + 7] : pw[bq + 5]};
      pa[kt * 2 + 0] = __builtin_bit_cast(s16x8, f0);
      pa[kt * 2 + 1] = __builtin_bit_cast(s16x8, f1);
    }

    // ---- O += P V
    const char* vbase = reinterpret_cast<const char*>(v_lds[bf]);
    __builtin_amdgcn_s_setprio(1);
#pragma unroll
    for (int ks = 0; ks < 4; ++ks) {
#pragma unroll
      for (int nt = 0; nt < 4; ++nt) {
        int d = nt * 32 + col;
        int slot = (ks * 2 + hi) ^ (d & 7);
        s16x8 bv = *reinterpret_cast<const s16x8*>(vbase + d * 128 + slot * 16);
        oacc[nt] = mfma32(pa[ks], bv, oacc[nt]);
      }
    }
    __builtin_amdgcn_s_setprio(0);

    if (kb < 31 && w < 4) write_v(bf ^ 1);
    __syncthreads();
  }

  float invl = 1.f / L;
#pragma unroll
  for (int r = 0; r < 16; ++r) {
    int qr = (r & 3) + 8 * (r >> 2) + 4 * hi;
    float il = __shfl(invl, qr);
    size_t row = (size_t)b * 2048 + qrow0 + qr;
#pragma unroll
    for (int nt = 0; nt < 4; ++nt)
      aout[row * 1024 + h * 128 + nt * 32 + col] = f2bf(oacc[nt][r] * il);
  }
}

// ---------------- launch ----------------

extern "C" void kernel_launch(void* const* d_in, const int* in_sizes, int n_in,
                              void* d_out, int out_size, void* d_ws, size_t ws_size,
                              hipStream_t stream) {
  const float* x     = (const float*)d_in[0];   // [8192, 1024]
  const float* wqkv  = (const float*)d_in[1];   // [3072, 1024]
  const float* wproj = (const float*)d_in[2];   // [1024, 1024]
  float* out = (float*)d_out;                   // [8192, 1024] fp32

  char* ws = (char*)d_ws;
  short* xb     = (short*)(ws);                          // 16,777,216 B
  short* wqkvb  = (short*)(ws + 16777216);               //  6,291,456 B
  short* wprojb = (short*)(ws + 23068672);               //  2,097,152 B
  short* qkvb   = (short*)(ws + 25165824);               // 50,331,648 B
  short* aoutb  = (short*)(ws + 75497472);               // 16,777,216 B (total ~92.3MB)

  cast3_kernel<<<2048, 256, 0, stream>>>(x, wqkv, wproj,
      (unsigned short*)xb, (unsigned short*)wqkvb, (unsigned short*)wprojb);

  // QKV: M=8192, N=3072, K=1024 -> grid 32*12 = 384 (384%8==0)
  gemm256<true><<<384, 512, 0, stream>>>(xb, wqkvb, (void*)qkvb, 8192, 3072, 1024);

  attn_fwd<<<32 * 8, 512, 0, stream>>>(qkvb, (unsigned short*)aoutb);

  // proj: M=8192, N=1024, K=1024 -> grid 32*4 = 128 (128%8==0)
  gemm256<false><<<128, 512, 0, stream>>>(aoutb, wprojb, (void*)out, 8192, 1024, 1024);
}